// Round 6
// baseline (83.576 us; speedup 1.0000x reference)
//
#include <hip/hip_runtime.h>
#include <math.h>

#define B_ 2
#define N_ 2048
#define H_ 16

typedef _Float16 f16x4 __attribute__((ext_vector_type(4)));
typedef float    f32x4 __attribute__((ext_vector_type(4)));

constexpr int THREADS = 512;   // 8 waves
constexpr int KSPLIT  = 4;     // key-split across blocks (exact fp32 merge)
constexpr int PPB     = 16;    // 32-key pairs per block = 512 keys
constexpr int QCH     = 256;   // queries per block

__device__ __forceinline__ float ex2(float x) { return __builtin_amdgcn_exp2f(x); }

// ---- kernel 1: per-(bh, qchunk, keyhalf) partial attention sums ----
__global__ __launch_bounds__(THREADS, 8)
void g2attn_main(const float* __restrict__ o, const float* __restrict__ mix,
                 float* __restrict__ ws)
{
    __shared__ _Float16 sK[PPB * 32 * 8];  // 8 KiB: c2-scaled K frags, dim7 = -12
    __shared__ _Float16 sP[PPB * 28 * 8];  // 7 KiB: KV^T frags (raw), cols 0..6

    const int bh = blockIdx.y, b = bh >> 4, h = bh & (H_ - 1);
    const int qc = blockIdx.x >> 2, kh = blockIdx.x & 3;
    const int tid = threadIdx.x;
    const float* obase = o + ((size_t)b * N_ * 128) + h * 8;

    const float m0 = mix[h * 2 + 0], m1 = mix[h * 2 + 1];
    const float wk = 1.0f / (1.0f + __expf(m1 - m0));
    const float c2 = wk * 0.5453442457918520f;   // log2(e)/sqrt(7) * w_k

    // ---- stage this block's 512 key rows (1 row per thread) ----
    {
        const int i = tid;
        const int krow = kh * 512 + i;
        const float* src = obase + (size_t)krow * 128;
        const float4 va = *(const float4*)src;
        const float4 vb = *(const float4*)(src + 4);
        const float hd[7] = {va.y, va.z, va.w, vb.x, vb.y, vb.z, vb.w};
        const int kp = i >> 5, sub = (i >> 4) & 1, r = i & 15;
        f16x4 klo = {(_Float16)(c2*hd[0]), (_Float16)(c2*hd[1]), (_Float16)(c2*hd[2]), (_Float16)(c2*hd[3])};
        f16x4 khi = {(_Float16)(c2*hd[4]), (_Float16)(c2*hd[5]), (_Float16)(c2*hd[6]), (_Float16)(-12.0f)};
        *(f16x4*)&sK[((kp*32 + r)*8) + sub*4]      = klo;
        *(f16x4*)&sK[((kp*32 + 16 + r)*8) + sub*4] = khi;
        const int gw = r >> 2, jw = r & 3;
        #pragma unroll
        for (int c = 0; c < 7; ++c)
            sP[(kp*28 + gw*7 + c)*8 + sub*4 + jw] = (_Float16)hd[c];
    }

    const int lane = tid & 63, wave = tid >> 6;
    const int cc = lane & 15, g = lane >> 4;

    const f16x4 z4   = {(_Float16)0.f, (_Float16)0.f, (_Float16)0.f, (_Float16)0.f};
    const f16x4 one4 = {(_Float16)1.f, (_Float16)1.f, (_Float16)1.f, (_Float16)1.f};
    const f32x4 zf   = {0.f, 0.f, 0.f, 0.f};

    // ---- Q B-frags straight from global (raw values, dim7 = +1) ----
    f16x4 qb0 = z4, qb1 = z4;
    if (lane < 32) {
        const int q0 = qc * QCH + wave * 32 + cc;     // tile t0 row cc
        const float* rA = obase + (size_t)q0 * 128;
        const float* rB = rA + 16 * 128;
        const float4 a0 = *(const float4*)rA;
        const float4 a1 = *(const float4*)(rA + 4);
        const float4 b0 = *(const float4*)rB;
        const float4 b1 = *(const float4*)(rB + 4);
        if (g == 0) {
            qb0 = (f16x4){(_Float16)a0.y, (_Float16)a0.z, (_Float16)a0.w, (_Float16)a1.x};
            qb1 = (f16x4){(_Float16)b0.y, (_Float16)b0.z, (_Float16)b0.w, (_Float16)b1.x};
        } else {
            qb0 = (f16x4){(_Float16)a1.y, (_Float16)a1.z, (_Float16)a1.w, (_Float16)1.0f};
            qb1 = (f16x4){(_Float16)b1.y, (_Float16)b1.z, (_Float16)b1.w, (_Float16)1.0f};
        }
    }
    __syncthreads();

    auto loadPair = [&](int p, f16x4& a0, f16x4& a1, f16x4& b0, f16x4& b1) {
        if (lane < 32) {
            const f16x4* s = (const f16x4*)&sK[(p*32 + lane)*8];
            a0 = s[0]; a1 = s[1];
        } else { a0 = z4; a1 = z4; }
        if (cc < 7) {
            const f16x4* s = (const f16x4*)&sP[(p*28 + g*7 + cc)*8];
            b0 = s[0]; b1 = s[1];
        } else if (cc == 7) { b0 = one4; b1 = one4; }
        else { b0 = z4; b1 = z4; }
    };

    f32x4 acc0 = zf, acc1 = zf;
    f16x4 ka0, ka1, pa0, pa1;
    loadPair(0, ka0, ka1, pa0, pa1);

    #define MKPB(S, PB) { \
        float e0 = ex2(S[0]), e1 = ex2(S[1]), e2 = ex2(S[2]), e3 = ex2(S[3]); \
        auto lo = __builtin_amdgcn_cvt_pkrtz(e0, e1); \
        auto hi = __builtin_amdgcn_cvt_pkrtz(e2, e3); \
        PB[0] = (_Float16)lo[0]; PB[1] = (_Float16)lo[1]; \
        PB[2] = (_Float16)hi[0]; PB[3] = (_Float16)hi[1]; }

    for (int p = 0; p < PPB; ++p) {
        f16x4 nk0, nk1, np0, np1;
        loadPair((p + 1) & (PPB - 1), nk0, nk1, np0, np1);

        // subtile keys 0-15: s = c2*dot(q,k) - 12 (scale+bias in frags)
        f32x4 s0 = __builtin_amdgcn_mfma_f32_16x16x16f16(ka0, qb0, zf, 0, 0, 0);
        f32x4 s1 = __builtin_amdgcn_mfma_f32_16x16x16f16(ka0, qb1, zf, 0, 0, 0);
        f16x4 pb0, pb1;
        MKPB(s0, pb0) MKPB(s1, pb1)
        acc0 = __builtin_amdgcn_mfma_f32_16x16x16f16(pa0, pb0, acc0, 0, 0, 0);
        acc1 = __builtin_amdgcn_mfma_f32_16x16x16f16(pa0, pb1, acc1, 0, 0, 0);

        // subtile keys 16-31
        f32x4 s2 = __builtin_amdgcn_mfma_f32_16x16x16f16(ka1, qb0, zf, 0, 0, 0);
        f32x4 s3 = __builtin_amdgcn_mfma_f32_16x16x16f16(ka1, qb1, zf, 0, 0, 0);
        f16x4 pb2, pb3;
        MKPB(s2, pb2) MKPB(s3, pb3)
        acc0 = __builtin_amdgcn_mfma_f32_16x16x16f16(pa1, pb2, acc0, 0, 0, 0);
        acc1 = __builtin_amdgcn_mfma_f32_16x16x16f16(pa1, pb3, acc1, 0, 0, 0);

        ka0 = nk0; ka1 = nk1; pa0 = np0; pa1 = np1;
    }
    #undef MKPB

    // ---- write C-frag partials (rows 0-7 = 7 dims + l) to workspace ----
    if (lane < 32) {
        const int q0 = qc * QCH + wave * 32 + cc;
        float* w0 = ws + ((((size_t)bh * N_ + q0) * 4 + kh) * 8) + g * 4;
        float* w1 = ws + ((((size_t)bh * N_ + q0 + 16) * 4 + kh) * 8) + g * 4;
        *(f32x4*)w0 = acc0;
        *(f32x4*)w1 = acc1;
    }
}

// ---- kernel 2: merge KSPLIT partials + epilogue (cross, gate, normalize) ----
__global__ __launch_bounds__(256, 8)
void g2attn_fin(const float* __restrict__ o, const float* __restrict__ ws,
                const float* __restrict__ alpha, const float* __restrict__ beta,
                float* __restrict__ out)
{
    const int gid = blockIdx.x * 256 + threadIdx.x;  // (b*N + q)*H + h, h fastest
    const int h = gid & (H_ - 1);
    const int bq = gid >> 4;                         // b*N + q
    const int b = bq >> 11;
    const int bh = b * H_ + h;
    const int q = bq & (N_ - 1);

    const float* p = ws + (((size_t)bh * N_ + q) * 4) * 8;
    float e[8] = {0.f, 0.f, 0.f, 0.f, 0.f, 0.f, 0.f, 0.f};
    #pragma unroll
    for (int kh = 0; kh < 4; ++kh) {
        const float4 a = *(const float4*)(p + kh * 8);
        const float4 c = *(const float4*)(p + kh * 8 + 4);
        e[0] += a.x; e[1] += a.y; e[2] += a.z; e[3] += a.w;
        e[4] += c.x; e[5] += c.y; e[6] += c.z; e[7] += c.w;
    }
    const float invl = 1.0f / e[7];

    const float* src = o + (size_t)bq * 128 + h * 8;
    const float4 va = *(const float4*)src;
    const float4 vb = *(const float4*)(src + 4);
    const float realv = va.x;
    const float qf[7] = {va.y, va.z, va.w, vb.x, vb.y, vb.z, vb.w};

    float ya[7];
    #pragma unroll
    for (int d = 0; d < 7; ++d) ya[d] = e[d] * invl;

    float xa[7] = {0.f, 0.f, 0.f, 0.f, 0.f, 0.f, 0.f};
    const int TR[7][3] = {{0,1,2},{0,3,4},{0,6,5},{1,3,5},{1,4,6},{2,3,6},{2,5,4}};
    #pragma unroll
    for (int t = 0; t < 7; ++t) {
        const int i = TR[t][0], j = TR[t][1], k = TR[t][2];
        xa[k] += qf[i]*ya[j] - qf[j]*ya[i];
        xa[i] += qf[j]*ya[k] - qf[k]*ya[j];
        xa[j] += qf[k]*ya[i] - qf[i]*ya[k];
    }

    const float sa = 1.0f / (1.0f + __expf(-alpha[h]));
    const float tb = tanhf(beta[h]);

    float im[7], nsq = realv * realv;
    #pragma unroll
    for (int d = 0; d < 7; ++d) {
        im[d] = sa*ya[d] + tb*xa[d];
        nsq = fmaf(im[d], im[d], nsq);
    }
    const float inv = 1.0f / fmaxf(sqrtf(nsq), 1e-12f);

    float* dst = out + (size_t)bq * 128 + h * 8;
    float4 oA = {realv*inv, im[0]*inv, im[1]*inv, im[2]*inv};
    float4 oB = {im[3]*inv, im[4]*inv, im[5]*inv, im[6]*inv};
    *(float4*)dst       = oA;
    *(float4*)(dst + 4) = oB;
}

extern "C" void kernel_launch(void* const* d_in, const int* in_sizes, int n_in,
                              void* d_out, int out_size, void* d_ws, size_t ws_size,
                              hipStream_t stream) {
    const float* o     = (const float*)d_in[0];
    const float* mix   = (const float*)d_in[1];
    const float* alpha = (const float*)d_in[2];
    const float* beta  = (const float*)d_in[3];
    float* out = (float*)d_out;
    float* ws  = (float*)d_ws;   // needs 32*2048*4*8*4B = 8 MB

    dim3 grid1((N_ / QCH) * KSPLIT, B_ * H_);   // 32 x 32 = 1024 blocks
    g2attn_main<<<grid1, THREADS, 0, stream>>>(o, mix, ws);

    dim3 grid2((B_ * N_ * H_) / 256);           // 256 blocks x 256 thr
    g2attn_fin<<<grid2, 256, 0, stream>>>(o, ws, alpha, beta, out);
}